// Round 1
// baseline (95.201 us; speedup 1.0000x reference)
//
#include <hip/hip_runtime.h>

// Problem constants (fixed by setup_inputs in the reference)
constexpr int N_  = 8;
constexpr int B_  = 64;
constexpr int C_  = 32;
constexpr int H_  = 256;
constexpr int W_  = 256;
constexpr int PH_ = 8;

__global__ __launch_bounds__(256)
void boxpool_kernel(const float* __restrict__ x, const float* __restrict__ boxes,
                    float* __restrict__ out, int MW, long featsSize, long total)
{
    const float halfW = (float)W_ * 0.5f;
    const float halfH = (float)H_ * 0.5f;
    const long stride = (long)gridDim.x * 256;

    for (long idx = (long)blockIdx.x * 256 + threadIdx.x; idx < total; idx += stride) {
        if (idx >= featsSize) {
            // widths tail: layout (N, B, 2)
            long w = idx - featsSize;
            int b = (int)((w >> 1) % B_);
            int n = (int)((w >> 1) / B_);
            const float* bp = boxes + ((long)(n * B_ + b)) * 4;
            float xmin = bp[0], ymin = bp[1], xmax = bp[2], ymax = bp[3];
            bool is_zero = (xmin == 0.f) && (ymin == 0.f) && (xmax == 0.f) && (ymax == 0.f);
            float bw = xmax - xmin, bh = ymax - ymin;
            bool wide = bw > bh;
            float den = wide ? bh : bw;
            den = (den == 0.f) ? 1.f : den;
            float ratio = (wide ? bw : bh) / den;
            float wf = ceilf(ratio * (float)PH_);
            out[idx] = is_zero ? 0.f : wf;
            continue;
        }

        // feats: layout (N, B, 2, C, PH, MW), j fastest
        int j = (int)(idx % MW);
        long t = idx / MW;
        int i = (int)(t & 7);  t >>= 3;
        int c = (int)(t & 31); t >>= 5;
        int d = (int)(t & 1);  t >>= 1;
        int b = (int)(t % B_);
        int n = (int)(t / B_);

        const float* bp = boxes + ((long)(n * B_ + b)) * 4;
        float xmin = bp[0], ymin = bp[1], xmax = bp[2], ymax = bp[3];
        bool is_zero = (xmin == 0.f) && (ymin == 0.f) && (xmax == 0.f) && (ymax == 0.f);
        float bw = xmax - xmin, bh = ymax - ymin;
        bool wide = bw > bh;
        float den = wide ? bh : bw;
        den = (den == 0.f) ? 1.f : den;
        float ratio = (wide ? bw : bh) / den;
        float wf = ceilf(ratio * (float)PH_);

        bool valid = ((float)j < wf) && !is_zero;
        if (!valid) { out[idx] = 0.f; continue; }

        float wm1 = (wf > 1.f) ? (wf - 1.f) : 1.f;
        float fi = (float)i, fj = (float)j;
        if (d == 1) { fi = (float)(PH_ - 1) - fi; fj = wf - 1.f - fj; }

        float gx, gy;
        if (wide) {
            float each_w = bw / wm1;
            float each_h = bh / (float)(PH_ - 1);
            gx = (xmin + fj * each_w - halfW) / halfW;
            gy = (ymin + fi * each_h - halfH) / halfH;
        } else {
            float each_w = bh / wm1;
            float each_h = bw / (float)(PH_ - 1);
            gx = (xmin + fi * each_h - halfW) / halfW;
            gy = ((wf - fj) * each_w + ymin - halfH) / halfH;
        }

        // grid_sample: bilinear, zeros padding, align_corners=False
        float ix = ((gx + 1.f) * (float)W_ - 1.f) * 0.5f;
        float iy = ((gy + 1.f) * (float)H_ - 1.f) * 0.5f;
        float x0f = floorf(ix);
        float y0f = floorf(iy);

        const float* xp = x + ((long)(n * C_ + c)) * (long)(H_ * W_);
        float acc = 0.f;
        #pragma unroll
        for (int dy = 0; dy <= 1; ++dy) {
            float yif = y0f + (float)dy;
            float wy  = 1.f - fabsf(iy - yif);
            bool  vy  = (yif >= 0.f) && (yif < (float)H_);
            int   yc  = (int)fminf(fmaxf(yif, 0.f), (float)(H_ - 1));
            #pragma unroll
            for (int dx = 0; dx <= 1; ++dx) {
                float xif = x0f + (float)dx;
                float wx  = 1.f - fabsf(ix - xif);
                bool  vx  = (xif >= 0.f) && (xif < (float)W_);
                int   xc  = (int)fminf(fmaxf(xif, 0.f), (float)(W_ - 1));
                if (vx && vy) acc += xp[(long)yc * W_ + xc] * (wx * wy);
            }
        }
        out[idx] = acc;
    }
}

extern "C" void kernel_launch(void* const* d_in, const int* in_sizes, int n_in,
                              void* d_out, int out_size, void* d_ws, size_t ws_size,
                              hipStream_t stream)
{
    const float* x     = (const float*)d_in[0];
    const float* boxes = (const float*)d_in[1];
    float* out = (float*)d_out;

    long total      = (long)out_size;
    long widthsSize = (long)N_ * B_ * 2;
    long featsSize  = total - widthsSize;
    int  MW         = (int)(featsSize / ((long)N_ * B_ * 2 * C_ * PH_));

    int grid = 2048;  // grid-stride loop covers the rest
    hipLaunchKernelGGL(boxpool_kernel, dim3(grid), dim3(256), 0, stream,
                       x, boxes, out, MW, featsSize, total);
}